// Round 4
// baseline (1098.692 us; speedup 1.0000x reference)
//
#include <hip/hip_runtime.h>

#define EMBED 2560
#define HEADS 8
#define HDIM  320
#define BATCH 2
#define SEQ   2048
#define MTOT  (BATCH*SEQ)   // 4096
#define FTOT  (3*EMBED)     // 7680

using bf = __bf16;
typedef __bf16 bf16x8 __attribute__((ext_vector_type(8)));
typedef float  f32x4  __attribute__((ext_vector_type(4)));
typedef short  s16x8  __attribute__((ext_vector_type(8)));
typedef float  f32x4v __attribute__((ext_vector_type(4)));

__device__ __forceinline__ void gl_lds16(const bf* g, bf* l) {
    __builtin_amdgcn_global_load_lds(
        (const __attribute__((address_space(1))) void*)g,
        (__attribute__((address_space(3))) void*)l,
        16, 0, 0);
}

// ---------------- fp32 -> bf16 convert ----------------
__global__ void cvt_bf16(const float* __restrict__ in, bf* __restrict__ out, int n) {
    int i = (blockIdx.x*blockDim.x + threadIdx.x)*8;
    if (i >= n) return;
    f32x4v a = *reinterpret_cast<const f32x4v*>(in + i);
    f32x4v b = *reinterpret_cast<const f32x4v*>(in + i + 4);
    bf16x8 r;
    r[0]=(bf)a[0]; r[1]=(bf)a[1]; r[2]=(bf)a[2]; r[3]=(bf)a[3];
    r[4]=(bf)b[0]; r[5]=(bf)b[1]; r[6]=(bf)b[2]; r[7]=(bf)b[3];
    *reinterpret_cast<bf16x8*>(out + i) = r;
}

// ---------------- NT GEMM: C[M,N] = A[M,K] @ B[N,K]^T + bias ----------------
// m97 structure: 128x128 tile, BK=32, 4 waves (2x2 of 64x64), 16x16x32 bf16 MFMA.
template<bool OUTBF>
__global__ void gemm_bt(const bf* __restrict__ A, const bf* __restrict__ B,
                        const float* __restrict__ bias, void* __restrict__ Cp,
                        int M, int N, int K) {
    __shared__ bf As[128*32];
    __shared__ bf Bs[128*32];
    const int tid = threadIdx.x, lane = tid & 63, wid = tid >> 6;
    const int wr = wid >> 1, wc = wid & 1;
    const int m0 = blockIdx.y*128, n0 = blockIdx.x*128;
    const int l15 = lane & 15, l4 = lane >> 4;
    f32x4 acc[4][4] = {};

    for (int k0 = 0; k0 < K; k0 += 32) {
        #pragma unroll
        for (int j = 0; j < 2; ++j) {
            int ch  = wid*128 + j*64 + lane;      // 16B chunk index (512 per tile)
            int row = ch >> 2, col = (ch & 3)*8;  // [128 rows][4 chunks of 8 bf16]
            gl_lds16(A + (size_t)(m0 + row)*K + k0 + col, As + (wid*128 + j*64)*8);
            gl_lds16(B + (size_t)(n0 + row)*K + k0 + col, Bs + (wid*128 + j*64)*8);
        }
        __syncthreads();
        bf16x8 af[4], bfr[4];
        #pragma unroll
        for (int m = 0; m < 4; ++m)
            af[m] = *reinterpret_cast<const bf16x8*>(&As[(wr*64 + m*16 + l15)*32 + l4*8]);
        #pragma unroll
        for (int n = 0; n < 4; ++n)
            bfr[n] = *reinterpret_cast<const bf16x8*>(&Bs[(wc*64 + n*16 + l15)*32 + l4*8]);
        #pragma unroll
        for (int m = 0; m < 4; ++m)
            #pragma unroll
            for (int n = 0; n < 4; ++n)
                acc[m][n] = __builtin_amdgcn_mfma_f32_16x16x32_bf16(af[m], bfr[n], acc[m][n], 0, 0, 0);
        __syncthreads();
    }
    // epilogue: C row=(lane>>4)*4+reg, col=lane&15 (m89-verified layout)
    #pragma unroll
    for (int m = 0; m < 4; ++m) {
        #pragma unroll
        for (int n = 0; n < 4; ++n) {
            int col_g = n0 + wc*64 + n*16 + l15;
            float bv = bias[col_g];
            #pragma unroll
            for (int r = 0; r < 4; ++r) {
                int row_g = m0 + wr*64 + m*16 + l4*4 + r;
                float v = acc[m][n][r] + bv;
                if (OUTBF) ((bf*)Cp)[(size_t)row_g*N + col_g] = (bf)v;
                else       ((float*)Cp)[(size_t)row_g*N + col_g] = v;
            }
        }
    }
}

// ---------------- V repack: qkv[b,s,2E + h*D + d] -> vt[bh, d, s] ----------------
__global__ void repack_vt(const bf* __restrict__ qkv, bf* __restrict__ vt) {
    __shared__ bf tile[64][72];
    const int bh = blockIdx.z, b = bh >> 3, h = bh & 7;
    const int s0 = blockIdx.x*64, d0 = blockIdx.y*64;
    const int t = threadIdx.x;
    #pragma unroll
    for (int p = 0; p < 2; ++p) {
        int sr = (t >> 3) + p*32, ck = t & 7;
        s16x8 v = *reinterpret_cast<const s16x8*>(
            qkv + ((size_t)(b*SEQ + s0 + sr))*FTOT + 2*EMBED + h*HDIM + d0 + ck*8);
        *reinterpret_cast<s16x8*>(&tile[sr][ck*8]) = v;
    }
    __syncthreads();
    #pragma unroll
    for (int p = 0; p < 2; ++p) {
        int dr = (t >> 3) + p*32, ck = t & 7;
        bf16x8 r;
        #pragma unroll
        for (int j = 0; j < 8; ++j) r[j] = tile[ck*8 + j][dr];
        *reinterpret_cast<bf16x8*>(vt + ((size_t)bh*HDIM + d0 + dr)*SEQ + s0 + ck*8) = r;
    }
}

// ---------------- flash attention v2 ----------------
// grid (32 q-tiles, 16 bh), 256 threads = 4 waves x 16 q-rows, KV tile = 32 keys
// 51.7KB LDS -> 3 blocks/CU; T14 async-stage; T13 defer-max; deferred l-reduce.
__global__ __launch_bounds__(256, 3)
void attn_fwd(const bf* __restrict__ qkv, const bf* __restrict__ vt, bf* __restrict__ aout) {
    __shared__ bf Ks[32][328];    // 32 keys x 320 d, +8 pad
    __shared__ bf Vs[320][40];    // 320 d x 32 keys, +8 pad
    __shared__ bf Ps[4][16][40];  // per-wave P round-trip
    const int bh = blockIdx.y, b = bh >> 3, h = bh & 7;
    const int tid = threadIdx.x, lane = tid & 63, wid = tid >> 6;
    const int q0 = blockIdx.x*64;
    const int qw = q0 + wid*16;
    const int l15 = lane & 15, l4 = lane >> 4;
    const float scale = 0.05590169944f;  // 1/sqrt(320)

    // staging geometry (fixed per thread): 2560 chunks of 16B over 256 threads
    int krow[5], kcol[5], vrow[5], vcol[5];
    #pragma unroll
    for (int i = 0; i < 5; ++i) {
        int ch = tid + i*256;
        krow[i] = ch/40; kcol[i] = ch - krow[i]*40;   // K: 32 rows x 40 chunks
        vrow[i] = ch>>2; vcol[i] = ch&3;              // Vt: 320 rows x 4 chunks
    }
    const bf* kbase = qkv + (size_t)b*SEQ*FTOT + EMBED + h*HDIM;
    const bf* vbase = vt + (size_t)bh*HDIM*SEQ;

    // hoist Q fragments (16 rows x 320 d = 10 frags)
    bf16x8 qf[10];
    const bf* qbase = qkv + ((size_t)(b*SEQ + qw + l15))*FTOT + h*HDIM + l4*8;
    #pragma unroll
    for (int d = 0; d < 10; ++d) qf[d] = *reinterpret_cast<const bf16x8*>(qbase + d*32);

    f32x4 o[20] = {};
    float mrow[4], lsum[4];
    #pragma unroll
    for (int r = 0; r < 4; ++r) { mrow[r] = -1e30f; lsum[r] = 0.f; }

    // T14: prefetch tile 0 into registers
    s16x8 kreg[5], vreg[5];
    #pragma unroll
    for (int i = 0; i < 5; ++i) {
        kreg[i] = *reinterpret_cast<const s16x8*>(kbase + (size_t)krow[i]*FTOT + kcol[i]*8);
        vreg[i] = *reinterpret_cast<const s16x8*>(vbase + (size_t)vrow[i]*SEQ + vcol[i]*8);
    }

    for (int kt = 0; kt < SEQ/32; ++kt) {
        __syncthreads();  // all waves done reading prev tile's LDS
        #pragma unroll
        for (int i = 0; i < 5; ++i) {
            *reinterpret_cast<s16x8*>(&Ks[krow[i]][kcol[i]*8]) = kreg[i];
            *reinterpret_cast<s16x8*>(&Vs[vrow[i]][vcol[i]*8]) = vreg[i];
        }
        __syncthreads();  // data ready
        if (kt + 1 < SEQ/32) {  // issue next tile's loads; latency hides under compute
            const int k0n = (kt + 1)*32;
            #pragma unroll
            for (int i = 0; i < 5; ++i) {
                kreg[i] = *reinterpret_cast<const s16x8*>(kbase + (size_t)(k0n + krow[i])*FTOT + kcol[i]*8);
                vreg[i] = *reinterpret_cast<const s16x8*>(vbase + (size_t)vrow[i]*SEQ + k0n + vcol[i]*8);
            }
        }

        // S = Q K^T  (scores[16q][32keys], C layout: row=l4*4+r, col=l15)
        f32x4 sc[2] = {};
        #pragma unroll
        for (int kb = 0; kb < 2; ++kb)
            #pragma unroll
            for (int d = 0; d < 10; ++d) {
                bf16x8 kf = *reinterpret_cast<const bf16x8*>(&Ks[kb*16 + l15][d*32 + l4*8]);
                sc[kb] = __builtin_amdgcn_mfma_f32_16x16x32_bf16(qf[d], kf, sc[kb], 0, 0, 0);
            }

        // online softmax: tile max + defer-max (T13, THR=8)
        float tmax[4];
        bool need = false;
        #pragma unroll
        for (int r = 0; r < 4; ++r) {
            float v = fmaxf(sc[0][r], sc[1][r])*scale;
            v = fmaxf(v, __shfl_xor(v, 1));
            v = fmaxf(v, __shfl_xor(v, 2));
            v = fmaxf(v, __shfl_xor(v, 4));
            v = fmaxf(v, __shfl_xor(v, 8));
            tmax[r] = v;
            need = need || (v > mrow[r] + 8.f);
        }
        if (__any(need)) {
            float alpha[4];
            #pragma unroll
            for (int r = 0; r < 4; ++r) {
                float nm = fmaxf(mrow[r], tmax[r]);
                alpha[r] = __expf(mrow[r] - nm);
                mrow[r] = nm;
                lsum[r] *= alpha[r];
            }
            #pragma unroll
            for (int c = 0; c < 20; ++c)
                #pragma unroll
                for (int r = 0; r < 4; ++r) o[c][r] *= alpha[r];
        }

        float ps[2][4];
        #pragma unroll
        for (int r = 0; r < 4; ++r) {
            float p0 = __expf(sc[0][r]*scale - mrow[r]);
            float p1 = __expf(sc[1][r]*scale - mrow[r]);
            ps[0][r] = p0; ps[1][r] = p1;
            lsum[r] += p0 + p1;   // per-lane partial; cross-lane reduce deferred to end
        }

        // P -> LDS (per-wave private) to reach MFMA A-fragment layout
        #pragma unroll
        for (int kb = 0; kb < 2; ++kb)
            #pragma unroll
            for (int r = 0; r < 4; ++r)
                Ps[wid][l4*4 + r][kb*16 + l15] = (bf)ps[kb][r];

        // O += P V  (A=P[16x32], B=Vt rows)
        bf16x8 pf = *reinterpret_cast<const bf16x8*>(&Ps[wid][l15][l4*8]);
        #pragma unroll
        for (int c = 0; c < 20; ++c) {
            bf16x8 vf = *reinterpret_cast<const bf16x8*>(&Vs[c*16 + l15][l4*8]);
            o[c] = __builtin_amdgcn_mfma_f32_16x16x32_bf16(pf, vf, o[c], 0, 0, 0);
        }
    }

    // final: cross-lane l reduce (16-lane row groups), then normalize + store
    float inv[4];
    #pragma unroll
    for (int r = 0; r < 4; ++r) {
        float s = lsum[r];
        s += __shfl_xor(s, 1);
        s += __shfl_xor(s, 2);
        s += __shfl_xor(s, 4);
        s += __shfl_xor(s, 8);
        inv[r] = 1.f/s;
    }
    #pragma unroll
    for (int c = 0; c < 20; ++c)
        #pragma unroll
        for (int r = 0; r < 4; ++r) {
            size_t idx = ((size_t)(b*SEQ + qw + l4*4 + r))*EMBED + h*HDIM + c*16 + l15;
            aout[idx] = (bf)(o[c][r]*inv[r]);
        }
}

// ---------------- launch ----------------
extern "C" void kernel_launch(void* const* d_in, const int* in_sizes, int n_in,
                              void* d_out, int out_size, void* d_ws, size_t ws_size,
                              hipStream_t stream) {
    const float* x    = (const float*)d_in[0];
    const float* Wqkv = (const float*)d_in[1];
    const float* bqkv = (const float*)d_in[2];
    const float* Wout = (const float*)d_in[3];
    const float* bout = (const float*)d_in[4];
    float* out = (float*)d_out;

    char* ws = (char*)d_ws;
    bf* xb    = (bf*)(ws);                         // 20,971,520 B
    bf* wqkvb = (bf*)(ws + 20971520);              // 39,321,600 B
    bf* woutb = (bf*)(ws + 60293120);              // 13,107,200 B
    bf* qkvb  = (bf*)(ws + 73400320);              // 62,914,560 B
    bf* vtb   = (bf*)(ws + 136314880);             // 20,971,520 B -> total 157,286,400
    bf* attnb = xb;                                // alias: x consumed by gemm1

    cvt_bf16<<<5120, 256, 0, stream>>>(x,    xb,    MTOT*EMBED);
    cvt_bf16<<<9600, 256, 0, stream>>>(Wqkv, wqkvb, FTOT*EMBED);
    cvt_bf16<<<3200, 256, 0, stream>>>(Wout, woutb, EMBED*EMBED);

    gemm_bt<true ><<<dim3(FTOT/128,  MTOT/128), 256, 0, stream>>>(xb, wqkvb, bqkv, qkvb, MTOT, FTOT, EMBED);
    repack_vt<<<dim3(SEQ/64, HDIM/64, BATCH*HEADS), 256, 0, stream>>>(qkvb, vtb);
    attn_fwd<<<dim3(SEQ/64, BATCH*HEADS), 256, 0, stream>>>(qkvb, vtb, attnb);
    gemm_bt<false><<<dim3(EMBED/128, MTOT/128), 256, 0, stream>>>(attnb, woutb, bout, out, MTOT, EMBED, EMBED);
}

// Round 5
// 492.159 us; speedup vs baseline: 2.2324x; 2.2324x over previous
//
#include <hip/hip_runtime.h>

#define EMBED 2560
#define HEADS 8
#define HDIM  320
#define BATCH 2
#define SEQ   2048
#define MTOT  (BATCH*SEQ)   // 4096
#define FTOT  (3*EMBED)     // 7680

using bf = __bf16;
typedef __bf16 bf16x8 __attribute__((ext_vector_type(8)));
typedef float  f32x4  __attribute__((ext_vector_type(4)));
typedef short  s16x8  __attribute__((ext_vector_type(8)));
typedef float  f32x4v __attribute__((ext_vector_type(4)));

__device__ __forceinline__ void gl_lds16(const bf* g, bf* l) {
    __builtin_amdgcn_global_load_lds(
        (const __attribute__((address_space(1))) void*)g,
        (__attribute__((address_space(3))) void*)l,
        16, 0, 0);
}

// ---------------- fp32 -> bf16 convert ----------------
__global__ void cvt_bf16(const float* __restrict__ in, bf* __restrict__ out, int n) {
    int i = (blockIdx.x*blockDim.x + threadIdx.x)*8;
    if (i >= n) return;
    f32x4v a = *reinterpret_cast<const f32x4v*>(in + i);
    f32x4v b = *reinterpret_cast<const f32x4v*>(in + i + 4);
    bf16x8 r;
    r[0]=(bf)a[0]; r[1]=(bf)a[1]; r[2]=(bf)a[2]; r[3]=(bf)a[3];
    r[4]=(bf)b[0]; r[5]=(bf)b[1]; r[6]=(bf)b[2]; r[7]=(bf)b[3];
    *reinterpret_cast<bf16x8*>(out + i) = r;
}

// ---------------- NT GEMM: C[M,N] = A[M,K] @ B[N,K]^T + bias ----------------
template<bool OUTBF>
__global__ void gemm_bt(const bf* __restrict__ A, const bf* __restrict__ B,
                        const float* __restrict__ bias, void* __restrict__ Cp,
                        int M, int N, int K) {
    __shared__ bf As[128*32];
    __shared__ bf Bs[128*32];
    const int tid = threadIdx.x, lane = tid & 63, wid = tid >> 6;
    const int wr = wid >> 1, wc = wid & 1;
    const int m0 = blockIdx.y*128, n0 = blockIdx.x*128;
    const int l15 = lane & 15, l4 = lane >> 4;
    f32x4 acc[4][4] = {};

    for (int k0 = 0; k0 < K; k0 += 32) {
        #pragma unroll
        for (int j = 0; j < 2; ++j) {
            int ch  = wid*128 + j*64 + lane;
            int row = ch >> 2, col = (ch & 3)*8;
            gl_lds16(A + (size_t)(m0 + row)*K + k0 + col, As + (wid*128 + j*64)*8);
            gl_lds16(B + (size_t)(n0 + row)*K + k0 + col, Bs + (wid*128 + j*64)*8);
        }
        __syncthreads();
        bf16x8 af[4], bfr[4];
        #pragma unroll
        for (int m = 0; m < 4; ++m)
            af[m] = *reinterpret_cast<const bf16x8*>(&As[(wr*64 + m*16 + l15)*32 + l4*8]);
        #pragma unroll
        for (int n = 0; n < 4; ++n)
            bfr[n] = *reinterpret_cast<const bf16x8*>(&Bs[(wc*64 + n*16 + l15)*32 + l4*8]);
        #pragma unroll
        for (int m = 0; m < 4; ++m)
            #pragma unroll
            for (int n = 0; n < 4; ++n)
                acc[m][n] = __builtin_amdgcn_mfma_f32_16x16x32_bf16(af[m], bfr[n], acc[m][n], 0, 0, 0);
        __syncthreads();
    }
    #pragma unroll
    for (int m = 0; m < 4; ++m) {
        #pragma unroll
        for (int n = 0; n < 4; ++n) {
            int col_g = n0 + wc*64 + n*16 + l15;
            float bv = bias[col_g];
            #pragma unroll
            for (int r = 0; r < 4; ++r) {
                int row_g = m0 + wr*64 + m*16 + l4*4 + r;
                float v = acc[m][n][r] + bv;
                if (OUTBF) ((bf*)Cp)[(size_t)row_g*N + col_g] = (bf)v;
                else       ((float*)Cp)[(size_t)row_g*N + col_g] = v;
            }
        }
    }
}

// ---------------- V repack: qkv[b,s,2E + h*D + d] -> vt[bh, d, s] ----------------
__global__ void repack_vt(const bf* __restrict__ qkv, bf* __restrict__ vt) {
    __shared__ bf tile[64][72];
    const int bh = blockIdx.z, b = bh >> 3, h = bh & 7;
    const int s0 = blockIdx.x*64, d0 = blockIdx.y*64;
    const int t = threadIdx.x;
    #pragma unroll
    for (int p = 0; p < 2; ++p) {
        int sr = (t >> 3) + p*32, ck = t & 7;
        s16x8 v = *reinterpret_cast<const s16x8*>(
            qkv + ((size_t)(b*SEQ + s0 + sr))*FTOT + 2*EMBED + h*HDIM + d0 + ck*8);
        *reinterpret_cast<s16x8*>(&tile[sr][ck*8]) = v;
    }
    __syncthreads();
    #pragma unroll
    for (int p = 0; p < 2; ++p) {
        int dr = (t >> 3) + p*32, ck = t & 7;
        bf16x8 r;
        #pragma unroll
        for (int j = 0; j < 8; ++j) r[j] = tile[ck*8 + j][dr];
        *reinterpret_cast<bf16x8*>(vt + ((size_t)bh*HDIM + d0 + dr)*SEQ + s0 + ck*8) = r;
    }
}

// ---------------- flash attention v3 ----------------
// grid (16 q-tiles, 16 bh) = 256 blocks (lockstep L2 reuse), 512 thr = 8 waves.
// Double-buffered K/V LDS via global_load_lds (no VGPR residency -> no spill),
// one barrier per KV tile, both-sides XOR swizzle (K: ^row&7, V: ^(row>>1)&3).
__global__ __launch_bounds__(512, 2)
void attn_fwd(const bf* __restrict__ qkv, const bf* __restrict__ vt, bf* __restrict__ aout) {
    __shared__ bf Kls[2][32*320];    // 20 KB x2, linear+swizzled (gl_lds dest)
    __shared__ bf Vls[2][320*32];    // 20 KB x2
    __shared__ bf Ps[8][16][40];     // per-wave P round-trip (10 KB)
    const int bh = blockIdx.y, b = bh >> 3, h = bh & 7;
    const int tid = threadIdx.x, lane = tid & 63, wid = tid >> 6;
    const int qw = blockIdx.x*128 + wid*16;
    const int l15 = lane & 15, l4 = lane >> 4;
    const float scale = 0.05590169944f;  // 1/sqrt(320)

    // --- staging setup: 2560 16B-chunks = 40 wave-groups; waves 0-3 K, 4-7 V ---
    const bf* gsrc[5];
    int ldsoff[5];
    size_t step;
    if (wid < 4) {
        step = (size_t)32*FTOT;
        #pragma unroll
        for (int i = 0; i < 5; ++i) {
            int g = wid*5 + i;               // 0..19
            int q = g*64 + lane;             // chunk id in K tile
            int r = q/40, cl = q - r*40;     // row, lds-chunk-in-row
            int cg = cl ^ (r & 7);           // global chunk (involution)
            gsrc[i] = qkv + (size_t)(b*SEQ + r)*FTOT + EMBED + h*HDIM + cg*8;
            ldsoff[i] = g*512;               // bf16 elems (1024B per group)
        }
    } else {
        step = 32;
        #pragma unroll
        for (int i = 0; i < 5; ++i) {
            int g = wid*5 + i - 20;          // 0..19
            int q = g*64 + lane;             // chunk id in V tile
            int row = q >> 2, cl = q & 3;
            int cg = cl ^ ((row >> 1) & 3);
            gsrc[i] = vt + (size_t)bh*HDIM*SEQ + (size_t)row*SEQ + cg*8;
            ldsoff[i] = g*512;
        }
    }

    // --- Q hoist: 16 rows x 320 d = 10 frags ---
    bf16x8 qf[10];
    const bf* qbase = qkv + ((size_t)(b*SEQ + qw + l15))*FTOT + h*HDIM + l4*8;
    #pragma unroll
    for (int d = 0; d < 10; ++d) qf[d] = *reinterpret_cast<const bf16x8*>(qbase + d*32);

    f32x4 o[20] = {};
    float mrow[4], lsum[4];
    #pragma unroll
    for (int r = 0; r < 4; ++r) { mrow[r] = -1e30f; lsum[r] = 0.f; }

    const int r7  = l15 & 7;                      // K read swizzle (R&7, same both kb)
    const int vsw = (l4 ^ ((l15 >> 1) & 3))*8;    // V read swizzle (lane-const)

    // prologue: stage tile 0 into buf 0
    {
        bf* lb = (wid < 4) ? &Kls[0][0] : &Vls[0][0];
        #pragma unroll
        for (int i = 0; i < 5; ++i) { gl_lds16(gsrc[i], lb + ldsoff[i]); gsrc[i] += step; }
    }
    __syncthreads();

    for (int kt = 0; kt < SEQ/32; ++kt) {
        const int bb = kt & 1;
        if (kt + 1 < SEQ/32) {   // stage next tile into other buffer (overlaps compute)
            bf* lb = (wid < 4) ? &Kls[bb^1][0] : &Vls[bb^1][0];
            #pragma unroll
            for (int i = 0; i < 5; ++i) { gl_lds16(gsrc[i], lb + ldsoff[i]); gsrc[i] += step; }
        }
        const bf* Kb = &Kls[bb][0];
        const bf* Vb = &Vls[bb][0];

        // S = Q K^T
        f32x4 sc[2] = {};
        #pragma unroll
        for (int kb = 0; kb < 2; ++kb) {
            const int Rbase = (kb*16 + l15)*320;
            #pragma unroll
            for (int d = 0; d < 10; ++d) {
                int c = (d*4 + l4) ^ r7;
                bf16x8 kf = *reinterpret_cast<const bf16x8*>(&Kb[Rbase + c*8]);
                sc[kb] = __builtin_amdgcn_mfma_f32_16x16x32_bf16(qf[d], kf, sc[kb], 0, 0, 0);
            }
        }

        // online softmax with defer-max (T13, THR=8)
        float tmax[4];
        bool need = false;
        #pragma unroll
        for (int r = 0; r < 4; ++r) {
            float v = fmaxf(sc[0][r], sc[1][r])*scale;
            v = fmaxf(v, __shfl_xor(v, 1));
            v = fmaxf(v, __shfl_xor(v, 2));
            v = fmaxf(v, __shfl_xor(v, 4));
            v = fmaxf(v, __shfl_xor(v, 8));
            tmax[r] = v;
            need = need || (v > mrow[r] + 8.f);
        }
        if (__any(need)) {
            float alpha[4];
            #pragma unroll
            for (int r = 0; r < 4; ++r) {
                float nm = fmaxf(mrow[r], tmax[r]);
                alpha[r] = __expf(mrow[r] - nm);
                mrow[r] = nm;
                lsum[r] *= alpha[r];
            }
            #pragma unroll
            for (int c = 0; c < 20; ++c)
                #pragma unroll
                for (int r = 0; r < 4; ++r) o[c][r] *= alpha[r];
        }

        float ps[2][4];
        #pragma unroll
        for (int r = 0; r < 4; ++r) {
            float p0 = __expf(sc[0][r]*scale - mrow[r]);
            float p1 = __expf(sc[1][r]*scale - mrow[r]);
            ps[0][r] = p0; ps[1][r] = p1;
            lsum[r] += p0 + p1;
        }

        #pragma unroll
        for (int kb = 0; kb < 2; ++kb)
            #pragma unroll
            for (int r = 0; r < 4; ++r)
                Ps[wid][l4*4 + r][kb*16 + l15] = (bf)ps[kb][r];

        // O += P V
        bf16x8 pf = *reinterpret_cast<const bf16x8*>(&Ps[wid][l15][l4*8]);
        #pragma unroll
        for (int c = 0; c < 20; ++c) {
            bf16x8 vf = *reinterpret_cast<const bf16x8*>(&Vb[(c*16 + l15)*32 + vsw]);
            o[c] = __builtin_amdgcn_mfma_f32_16x16x32_bf16(pf, vf, o[c], 0, 0, 0);
        }
        __syncthreads();  // waves done with buf bb; vmcnt drain completes buf bb^1
    }

    float inv[4];
    #pragma unroll
    for (int r = 0; r < 4; ++r) {
        float s = lsum[r];
        s += __shfl_xor(s, 1);
        s += __shfl_xor(s, 2);
        s += __shfl_xor(s, 4);
        s += __shfl_xor(s, 8);
        inv[r] = 1.f/s;
    }
    #pragma unroll
    for (int c = 0; c < 20; ++c)
        #pragma unroll
        for (int r = 0; r < 4; ++r) {
            size_t idx = ((size_t)(b*SEQ + qw + l4*4 + r))*EMBED + h*HDIM + c*16 + l15;
            aout[idx] = (bf)(o[c][r]*inv[r]);
        }
}

// ---------------- launch ----------------
extern "C" void kernel_launch(void* const* d_in, const int* in_sizes, int n_in,
                              void* d_out, int out_size, void* d_ws, size_t ws_size,
                              hipStream_t stream) {
    const float* x    = (const float*)d_in[0];
    const float* Wqkv = (const float*)d_in[1];
    const float* bqkv = (const float*)d_in[2];
    const float* Wout = (const float*)d_in[3];
    const float* bout = (const float*)d_in[4];
    float* out = (float*)d_out;

    char* ws = (char*)d_ws;
    bf* xb    = (bf*)(ws);                         // 20,971,520 B
    bf* wqkvb = (bf*)(ws + 20971520);              // 39,321,600 B
    bf* woutb = (bf*)(ws + 60293120);              // 13,107,200 B
    bf* qkvb  = (bf*)(ws + 73400320);              // 62,914,560 B
    bf* vtb   = (bf*)(ws + 136314880);             // 20,971,520 B -> total 157,286,400
    bf* attnb = xb;                                // alias: x consumed by gemm1

    cvt_bf16<<<5120, 256, 0, stream>>>(x,    xb,    MTOT*EMBED);
    cvt_bf16<<<9600, 256, 0, stream>>>(Wqkv, wqkvb, FTOT*EMBED);
    cvt_bf16<<<3200, 256, 0, stream>>>(Wout, woutb, EMBED*EMBED);

    gemm_bt<true ><<<dim3(FTOT/128,  MTOT/128), 256, 0, stream>>>(xb, wqkvb, bqkv, qkvb, MTOT, FTOT, EMBED);
    repack_vt<<<dim3(SEQ/64, HDIM/64, BATCH*HEADS), 256, 0, stream>>>(qkvb, vtb);
    attn_fwd<<<dim3(SEQ/128, BATCH*HEADS), 512, 0, stream>>>(qkvb, vtb, attnb);
    gemm_bt<false><<<dim3(EMBED/128, MTOT/128), 256, 0, stream>>>(attnb, woutb, bout, out, MTOT, EMBED, EMBED);
}

// Round 6
// 435.220 us; speedup vs baseline: 2.5245x; 1.1308x over previous
//
#include <hip/hip_runtime.h>

#define EMBED 2560
#define HEADS 8
#define HDIM  320
#define BATCH 2
#define SEQ   2048
#define MTOT  (BATCH*SEQ)   // 4096
#define FTOT  (3*EMBED)     // 7680

using bf = __bf16;
typedef __bf16 bf16x8 __attribute__((ext_vector_type(8)));
typedef float  f32x4  __attribute__((ext_vector_type(4)));
typedef short  s16x8  __attribute__((ext_vector_type(8)));
typedef float  f32x4v __attribute__((ext_vector_type(4)));

__device__ __forceinline__ void gl_lds16(const bf* g, bf* l) {
    __builtin_amdgcn_global_load_lds(
        (const __attribute__((address_space(1))) void*)g,
        (__attribute__((address_space(3))) void*)l,
        16, 0, 0);
}

// ---------------- fp32 -> bf16 convert ----------------
__global__ void cvt_bf16(const float* __restrict__ in, bf* __restrict__ out, int n) {
    int i = (blockIdx.x*blockDim.x + threadIdx.x)*8;
    if (i >= n) return;
    f32x4v a = *reinterpret_cast<const f32x4v*>(in + i);
    f32x4v b = *reinterpret_cast<const f32x4v*>(in + i + 4);
    bf16x8 r;
    r[0]=(bf)a[0]; r[1]=(bf)a[1]; r[2]=(bf)a[2]; r[3]=(bf)a[3];
    r[4]=(bf)b[0]; r[5]=(bf)b[1]; r[6]=(bf)b[2]; r[7]=(bf)b[3];
    *reinterpret_cast<bf16x8*>(out + i) = r;
}

// ============ 8-phase 256x256 NT GEMM: C[M,N] = A[M,K] @ B[N,K]^T + bias ============
// BK=64, 8 waves (2M x 4N), wave tile 128x64. LDS 128 KiB: 2buf x 2half x 128x64 x {A,B}.
// Counted vmcnt(4) once per K-tile (never 0 mid-loop); XOR swizzle granule^=(row&3)
// applied on BOTH sides (pre-swizzled global src for gl_lds, swizzled ds_read addr).
template<bool OUTBF>
__global__ __launch_bounds__(512, 2)
void gemm256(const bf* __restrict__ A, const bf* __restrict__ B,
             const float* __restrict__ bias, void* __restrict__ Cp,
             int M, int N, int K) {
    __shared__ __align__(16) bf AsL[2][2][8192];
    __shared__ __align__(16) bf BsL[2][2][8192];
    const int tid = threadIdx.x, lane = tid & 63, wid = tid >> 6;
    const int wr = wid >> 2, wc = wid & 3;
    const int l15 = lane & 15, l4 = lane >> 4;

    // bijective XCD swizzle (grids here are multiples of 8)
    const int nwg = gridDim.x*gridDim.y;
    int bid = blockIdx.y*gridDim.x + blockIdx.x;
    if ((nwg & 7) == 0) bid = (bid & 7)*(nwg >> 3) + (bid >> 3);
    const int m0 = (bid / gridDim.x)*256, n0 = (bid % gridDim.x)*256;
    const int NT = K >> 6;

    // staging geometry: per half-tile (128 rows x 64 cols), 1024 chunks of 16B,
    // thread stages chunks q = (wid*2+j)*64 + lane; LDS dest linear, global pre-swizzled.
    unsigned aOff[2];
    #pragma unroll
    for (int j = 0; j < 2; ++j) {
        int q = (wid*2 + j)*64 + lane;
        int r = q >> 3, cs = q & 7;
        int csrc = ((((cs >> 1) ^ (r & 3)) << 1) | (cs & 1));
        aOff[j] = (unsigned)r*K + csrc*8;
    }
    const bf* Ap = A + (size_t)m0*K;
    const bf* Bp = B + (size_t)n0*K;

    auto stA = [&](int bb, int h, int kt) {
        bf* d = &AsL[bb][h][wid*1024];
        const bf* s = Ap + (size_t)h*128*K + (size_t)kt*64;
        gl_lds16(s + aOff[0], d);
        gl_lds16(s + aOff[1], d + 512);
    };
    auto stB = [&](int bb, int h, int kt) {
        bf* d = &BsL[bb][h][wid*1024];
        const bf* s = Bp + (size_t)h*128*K + (size_t)kt*64;
        gl_lds16(s + aOff[0], d);
        gl_lds16(s + aOff[1], d + 512);
    };

    f32x4 acc[8][4] = {};
    bf16x8 aR[4][2], bR0[2][2], bR1[2][2];

    // prologue: exact steady-state issue order, then wait all of kt=0
    stB(0,0,0); stB(0,1,0); stA(0,0,0); stA(0,1,0); stB(1,0,1); stB(1,1,1);
    asm volatile("s_waitcnt vmcnt(4)" ::: "memory");
    __builtin_amdgcn_s_barrier();

    const int brow0 = (wc & 1)*64;   // B row-in-half base for this wave
    for (int kt = 0; kt < NT; ++kt) {
        const int bb = kt & 1;
        const bf* Ab = &AsL[bb][wr][0];
        const bf* Bb = &BsL[bb][wc >> 1][0];

        // ---- phase 1: quad (m0,n0). ds: A-sub0 (8) + B-sub0 (4). stage Ah0(kt+1).
        #pragma unroll
        for (int mi = 0; mi < 4; ++mi)
            #pragma unroll
            for (int kk = 0; kk < 2; ++kk) {
                int r = mi*16 + l15;
                int g = kk*2 + (l4 >> 1);
                aR[mi][kk] = *reinterpret_cast<const bf16x8*>(&Ab[r*64 + ((g^(r&3))*16) + (l4&1)*8]);
            }
        #pragma unroll
        for (int ni = 0; ni < 2; ++ni)
            #pragma unroll
            for (int kk = 0; kk < 2; ++kk) {
                int r = brow0 + ni*16 + l15;
                int g = kk*2 + (l4 >> 1);
                bR0[ni][kk] = *reinterpret_cast<const bf16x8*>(&Bb[r*64 + ((g^(r&3))*16) + (l4&1)*8]);
            }
        if (kt + 1 < NT) stA(bb^1, 0, kt+1);
        __builtin_amdgcn_s_barrier();
        asm volatile("s_waitcnt lgkmcnt(0)" ::: "memory");
        __builtin_amdgcn_sched_barrier(0);
        __builtin_amdgcn_s_setprio(1);
        #pragma unroll
        for (int mi = 0; mi < 4; ++mi)
            #pragma unroll
            for (int ni = 0; ni < 2; ++ni)
                #pragma unroll
                for (int kk = 0; kk < 2; ++kk)
                    acc[mi][ni] = __builtin_amdgcn_mfma_f32_16x16x32_bf16(aR[mi][kk], bR0[ni][kk], acc[mi][ni], 0, 0, 0);
        __builtin_amdgcn_s_setprio(0);
        __builtin_amdgcn_s_barrier();

        // ---- phase 2: quad (m0,n1). ds: B-sub1 (4). stage Ah1(kt+1).
        #pragma unroll
        for (int ni = 0; ni < 2; ++ni)
            #pragma unroll
            for (int kk = 0; kk < 2; ++kk) {
                int r = brow0 + 32 + ni*16 + l15;
                int g = kk*2 + (l4 >> 1);
                bR1[ni][kk] = *reinterpret_cast<const bf16x8*>(&Bb[r*64 + ((g^(r&3))*16) + (l4&1)*8]);
            }
        if (kt + 1 < NT) stA(bb^1, 1, kt+1);
        __builtin_amdgcn_s_barrier();
        asm volatile("s_waitcnt lgkmcnt(0)" ::: "memory");
        __builtin_amdgcn_sched_barrier(0);
        __builtin_amdgcn_s_setprio(1);
        #pragma unroll
        for (int mi = 0; mi < 4; ++mi)
            #pragma unroll
            for (int ni = 0; ni < 2; ++ni)
                #pragma unroll
                for (int kk = 0; kk < 2; ++kk)
                    acc[mi][2+ni] = __builtin_amdgcn_mfma_f32_16x16x32_bf16(aR[mi][kk], bR1[ni][kk], acc[mi][2+ni], 0, 0, 0);
        __builtin_amdgcn_s_setprio(0);
        __builtin_amdgcn_s_barrier();

        // ---- phase 3: quad (m1,n1). ds: A-sub1 (8, overwrite aR). stage Bh0(kt+2).
        #pragma unroll
        for (int mi = 0; mi < 4; ++mi)
            #pragma unroll
            for (int kk = 0; kk < 2; ++kk) {
                int r = 64 + mi*16 + l15;
                int g = kk*2 + (l4 >> 1);
                aR[mi][kk] = *reinterpret_cast<const bf16x8*>(&Ab[r*64 + ((g^(r&3))*16) + (l4&1)*8]);
            }
        if (kt + 2 < NT) stB(bb, 0, kt+2);
        __builtin_amdgcn_s_barrier();
        asm volatile("s_waitcnt lgkmcnt(0)" ::: "memory");
        __builtin_amdgcn_sched_barrier(0);
        __builtin_amdgcn_s_setprio(1);
        #pragma unroll
        for (int mi = 0; mi < 4; ++mi)
            #pragma unroll
            for (int ni = 0; ni < 2; ++ni)
                #pragma unroll
                for (int kk = 0; kk < 2; ++kk)
                    acc[4+mi][2+ni] = __builtin_amdgcn_mfma_f32_16x16x32_bf16(aR[mi][kk], bR1[ni][kk], acc[4+mi][2+ni], 0, 0, 0);
        __builtin_amdgcn_s_setprio(0);
        __builtin_amdgcn_s_barrier();

        // ---- phase 4: quad (m1,n0). no ds. stage Bh1(kt+2). counted vmcnt.
        if (kt + 2 < NT) stB(bb, 1, kt+2);
        if (kt >= NT-2) asm volatile("s_waitcnt vmcnt(0)" ::: "memory");
        else            asm volatile("s_waitcnt vmcnt(4)" ::: "memory");
        __builtin_amdgcn_s_barrier();
        __builtin_amdgcn_s_setprio(1);
        #pragma unroll
        for (int mi = 0; mi < 4; ++mi)
            #pragma unroll
            for (int ni = 0; ni < 2; ++ni)
                #pragma unroll
                for (int kk = 0; kk < 2; ++kk)
                    acc[4+mi][ni] = __builtin_amdgcn_mfma_f32_16x16x32_bf16(aR[mi][kk], bR0[ni][kk], acc[4+mi][ni], 0, 0, 0);
        __builtin_amdgcn_s_setprio(0);
        __builtin_amdgcn_s_barrier();
    }

    // epilogue
    const int cr0 = m0 + wr*128, cc0 = n0 + wc*64;
    #pragma unroll
    for (int NI = 0; NI < 4; ++NI) {
        int colg = cc0 + NI*16 + l15;
        float bv = bias[colg];
        #pragma unroll
        for (int MI = 0; MI < 8; ++MI)
            #pragma unroll
            for (int rr = 0; rr < 4; ++rr) {
                int rowg = cr0 + MI*16 + l4*4 + rr;
                float v = acc[MI][NI][rr] + bv;
                if (OUTBF) ((bf*)Cp)[(size_t)rowg*N + colg] = (bf)v;
                else       ((float*)Cp)[(size_t)rowg*N + colg] = v;
            }
    }
}

// ---------------- V repack: qkv[b,s,2E + h*D + d] -> vt[bh, d, s] ----------------
__global__ void repack_vt(const bf* __restrict__ qkv, bf* __restrict__ vt) {
    __shared__ bf tile[64][72];
    const int bh = blockIdx.z, b = bh >> 3, h = bh & 7;
    const int s0 = blockIdx.x*64, d0 = blockIdx.y*64;
    const int t = threadIdx.x;
    #pragma unroll
    for (int p = 0; p < 2; ++p) {
        int sr = (t >> 3) + p*32, ck = t & 7;
        s16x8 v = *reinterpret_cast<const s16x8*>(
            qkv + ((size_t)(b*SEQ + s0 + sr))*FTOT + 2*EMBED + h*HDIM + d0 + ck*8);
        *reinterpret_cast<s16x8*>(&tile[sr][ck*8]) = v;
    }
    __syncthreads();
    #pragma unroll
    for (int p = 0; p < 2; ++p) {
        int dr = (t >> 3) + p*32, ck = t & 7;
        bf16x8 r;
        #pragma unroll
        for (int j = 0; j < 8; ++j) r[j] = tile[ck*8 + j][dr];
        *reinterpret_cast<bf16x8*>(vt + ((size_t)bh*HDIM + d0 + dr)*SEQ + s0 + ck*8) = r;
    }
}

// ---------------- flash attention v3 (unchanged from round 5) ----------------
__global__ __launch_bounds__(512, 2)
void attn_fwd(const bf* __restrict__ qkv, const bf* __restrict__ vt, bf* __restrict__ aout) {
    __shared__ bf Kls[2][32*320];
    __shared__ bf Vls[2][320*32];
    __shared__ bf Ps[8][16][40];
    const int bh = blockIdx.y, b = bh >> 3, h = bh & 7;
    const int tid = threadIdx.x, lane = tid & 63, wid = tid >> 6;
    const int qw = blockIdx.x*128 + wid*16;
    const int l15 = lane & 15, l4 = lane >> 4;
    const float scale = 0.05590169944f;

    const bf* gsrc[5];
    int ldsoff[5];
    size_t step;
    if (wid < 4) {
        step = (size_t)32*FTOT;
        #pragma unroll
        for (int i = 0; i < 5; ++i) {
            int g = wid*5 + i;
            int q = g*64 + lane;
            int r = q/40, cl = q - r*40;
            int cg = cl ^ (r & 7);
            gsrc[i] = qkv + (size_t)(b*SEQ + r)*FTOT + EMBED + h*HDIM + cg*8;
            ldsoff[i] = g*512;
        }
    } else {
        step = 32;
        #pragma unroll
        for (int i = 0; i < 5; ++i) {
            int g = wid*5 + i - 20;
            int q = g*64 + lane;
            int row = q >> 2, cl = q & 3;
            int cg = cl ^ ((row >> 1) & 3);
            gsrc[i] = vt + (size_t)bh*HDIM*SEQ + (size_t)row*SEQ + cg*8;
            ldsoff[i] = g*512;
        }
    }

    bf16x8 qf[10];
    const bf* qbase = qkv + ((size_t)(b*SEQ + qw + l15))*FTOT + h*HDIM + l4*8;
    #pragma unroll
    for (int d = 0; d < 10; ++d) qf[d] = *reinterpret_cast<const bf16x8*>(qbase + d*32);

    f32x4 o[20] = {};
    float mrow[4], lsum[4];
    #pragma unroll
    for (int r = 0; r < 4; ++r) { mrow[r] = -1e30f; lsum[r] = 0.f; }

    const int r7  = l15 & 7;
    const int vsw = (l4 ^ ((l15 >> 1) & 3))*8;

    {
        bf* lb = (wid < 4) ? &Kls[0][0] : &Vls[0][0];
        #pragma unroll
        for (int i = 0; i < 5; ++i) { gl_lds16(gsrc[i], lb + ldsoff[i]); gsrc[i] += step; }
    }
    __syncthreads();

    for (int kt = 0; kt < SEQ/32; ++kt) {
        const int bb = kt & 1;
        if (kt + 1 < SEQ/32) {
            bf* lb = (wid < 4) ? &Kls[bb^1][0] : &Vls[bb^1][0];
            #pragma unroll
            for (int i = 0; i < 5; ++i) { gl_lds16(gsrc[i], lb + ldsoff[i]); gsrc[i] += step; }
        }
        const bf* Kb = &Kls[bb][0];
        const bf* Vb = &Vls[bb][0];

        f32x4 sc[2] = {};
        #pragma unroll
        for (int kb = 0; kb < 2; ++kb) {
            const int Rbase = (kb*16 + l15)*320;
            #pragma unroll
            for (int d = 0; d < 10; ++d) {
                int c = (d*4 + l4) ^ r7;
                bf16x8 kf = *reinterpret_cast<const bf16x8*>(&Kb[Rbase + c*8]);
                sc[kb] = __builtin_amdgcn_mfma_f32_16x16x32_bf16(qf[d], kf, sc[kb], 0, 0, 0);
            }
        }

        float tmax[4];
        bool need = false;
        #pragma unroll
        for (int r = 0; r < 4; ++r) {
            float v = fmaxf(sc[0][r], sc[1][r])*scale;
            v = fmaxf(v, __shfl_xor(v, 1));
            v = fmaxf(v, __shfl_xor(v, 2));
            v = fmaxf(v, __shfl_xor(v, 4));
            v = fmaxf(v, __shfl_xor(v, 8));
            tmax[r] = v;
            need = need || (v > mrow[r] + 8.f);
        }
        if (__any(need)) {
            float alpha[4];
            #pragma unroll
            for (int r = 0; r < 4; ++r) {
                float nm = fmaxf(mrow[r], tmax[r]);
                alpha[r] = __expf(mrow[r] - nm);
                mrow[r] = nm;
                lsum[r] *= alpha[r];
            }
            #pragma unroll
            for (int c = 0; c < 20; ++c)
                #pragma unroll
                for (int r = 0; r < 4; ++r) o[c][r] *= alpha[r];
        }

        float ps[2][4];
        #pragma unroll
        for (int r = 0; r < 4; ++r) {
            float p0 = __expf(sc[0][r]*scale - mrow[r]);
            float p1 = __expf(sc[1][r]*scale - mrow[r]);
            ps[0][r] = p0; ps[1][r] = p1;
            lsum[r] += p0 + p1;
        }

        #pragma unroll
        for (int kb = 0; kb < 2; ++kb)
            #pragma unroll
            for (int r = 0; r < 4; ++r)
                Ps[wid][l4*4 + r][kb*16 + l15] = (bf)ps[kb][r];

        bf16x8 pf = *reinterpret_cast<const bf16x8*>(&Ps[wid][l15][l4*8]);
        #pragma unroll
        for (int c = 0; c < 20; ++c) {
            bf16x8 vf = *reinterpret_cast<const bf16x8*>(&Vb[(c*16 + l15)*32 + vsw]);
            o[c] = __builtin_amdgcn_mfma_f32_16x16x32_bf16(pf, vf, o[c], 0, 0, 0);
        }
        __syncthreads();
    }

    float inv[4];
    #pragma unroll
    for (int r = 0; r < 4; ++r) {
        float s = lsum[r];
        s += __shfl_xor(s, 1);
        s += __shfl_xor(s, 2);
        s += __shfl_xor(s, 4);
        s += __shfl_xor(s, 8);
        inv[r] = 1.f/s;
    }
    #pragma unroll
    for (int c = 0; c < 20; ++c)
        #pragma unroll
        for (int r = 0; r < 4; ++r) {
            size_t idx = ((size_t)(b*SEQ + qw + l4*4 + r))*EMBED + h*HDIM + c*16 + l15;
            aout[idx] = (bf)(o[c][r]*inv[r]);
        }
}

// ---------------- launch ----------------
extern "C" void kernel_launch(void* const* d_in, const int* in_sizes, int n_in,
                              void* d_out, int out_size, void* d_ws, size_t ws_size,
                              hipStream_t stream) {
    const float* x    = (const float*)d_in[0];
    const float* Wqkv = (const float*)d_in[1];
    const float* bqkv = (const float*)d_in[2];
    const float* Wout = (const float*)d_in[3];
    const float* bout = (const float*)d_in[4];
    float* out = (float*)d_out;

    char* ws = (char*)d_ws;
    bf* xb    = (bf*)(ws);                         // 20,971,520 B
    bf* wqkvb = (bf*)(ws + 20971520);              // 39,321,600 B
    bf* woutb = (bf*)(ws + 60293120);              // 13,107,200 B
    bf* qkvb  = (bf*)(ws + 73400320);              // 62,914,560 B
    bf* vtb   = (bf*)(ws + 136314880);             // 20,971,520 B -> total 157,286,400
    bf* attnb = xb;                                // alias: x consumed by gemm1

    cvt_bf16<<<5120, 256, 0, stream>>>(x,    xb,    MTOT*EMBED);
    cvt_bf16<<<9600, 256, 0, stream>>>(Wqkv, wqkvb, FTOT*EMBED);
    cvt_bf16<<<3200, 256, 0, stream>>>(Wout, woutb, EMBED*EMBED);

    gemm256<true ><<<dim3(FTOT/256,  MTOT/256), 512, 0, stream>>>(xb, wqkvb, bqkv, qkvb, MTOT, FTOT, EMBED);
    repack_vt<<<dim3(SEQ/64, HDIM/64, BATCH*HEADS), 256, 0, stream>>>(qkvb, vtb);
    attn_fwd<<<dim3(SEQ/128, BATCH*HEADS), 512, 0, stream>>>(qkvb, vtb, attnb);
    gemm256<false><<<dim3(EMBED/256, MTOT/256), 512, 0, stream>>>(attnb, woutb, bout, out, MTOT, EMBED, EMBED);
}

// Round 8
// 417.322 us; speedup vs baseline: 2.6327x; 1.0429x over previous
//
#include <hip/hip_runtime.h>

#define EMBED 2560
#define HEADS 8
#define HDIM  320
#define BATCH 2
#define SEQ   2048
#define MTOT  (BATCH*SEQ)   // 4096
#define FTOT  (3*EMBED)     // 7680

using bf = __bf16;
typedef __bf16 bf16x8 __attribute__((ext_vector_type(8)));
typedef float  f32x4  __attribute__((ext_vector_type(4)));
typedef short  s16x8  __attribute__((ext_vector_type(8)));
typedef float  f32x4v __attribute__((ext_vector_type(4)));

__device__ __forceinline__ void gl_lds16(const bf* g, bf* l) {
    __builtin_amdgcn_global_load_lds(
        (const __attribute__((address_space(1))) void*)g,
        (__attribute__((address_space(3))) void*)l,
        16, 0, 0);
}

// ---------------- fp32 -> bf16 convert ----------------
__global__ void cvt_bf16(const float* __restrict__ in, bf* __restrict__ out, int n) {
    int i = (blockIdx.x*blockDim.x + threadIdx.x)*8;
    if (i >= n) return;
    f32x4v a = *reinterpret_cast<const f32x4v*>(in + i);
    f32x4v b = *reinterpret_cast<const f32x4v*>(in + i + 4);
    bf16x8 r;
    r[0]=(bf)a[0]; r[1]=(bf)a[1]; r[2]=(bf)a[2]; r[3]=(bf)a[3];
    r[4]=(bf)b[0]; r[5]=(bf)b[1]; r[6]=(bf)b[2]; r[7]=(bf)b[3];
    *reinterpret_cast<bf16x8*>(out + i) = r;
}

// ============ 8-phase 256x256 NT GEMM: C[M,N] = A[M,K] @ B[N,K]^T + bias ============
// BK=64, 8 waves (2M x 4N), wave tile 128x64. LDS 128 KiB: 2buf x 2half x 128x64 x {A,B}.
// Counted vmcnt(4) once per K-tile. Full 3-bit XOR granule swizzle: within each 128B
// row (8 x 16B granules), k-granule kg stored at slot kg^(row&7). Read residue
// (kk*4+l4)^(l15&7) spans all 8 per 16-lane phase -> conflict-free ds_read_b128.
template<bool OUTBF>
__global__ __launch_bounds__(512, 2)
void gemm256(const bf* __restrict__ A, const bf* __restrict__ B,
             const float* __restrict__ bias, void* __restrict__ Cp,
             int M, int N, int K) {
    __shared__ __align__(16) bf AsL[2][2][8192];
    __shared__ __align__(16) bf BsL[2][2][8192];
    const int tid = threadIdx.x, lane = tid & 63, wid = tid >> 6;
    const int wr = wid >> 2, wc = wid & 3;
    const int l15 = lane & 15, l4 = lane >> 4;

    // bijective XCD swizzle (grids here are multiples of 8)
    const int nwg = gridDim.x*gridDim.y;
    int bid = blockIdx.y*gridDim.x + blockIdx.x;
    if ((nwg & 7) == 0) bid = (bid & 7)*(nwg >> 3) + (bid >> 3);
    const int m0 = (bid / gridDim.x)*256, n0 = (bid % gridDim.x)*256;
    const int NT = K >> 6;

    // staging: per half-tile (128 rows x 64 cols) = 1024 granules of 16B.
    // LDS linear dest; lane l of instr (wid*2+j) holds LDS granule q=(wid*2+j)*64+l
    // -> row=q>>3, slot c=q&7, global k-granule = c^(row&7).
    unsigned aOff[2];
    #pragma unroll
    for (int j = 0; j < 2; ++j) {
        int q = (wid*2 + j)*64 + lane;
        int r = q >> 3, c = q & 7;
        aOff[j] = (unsigned)r*K + (unsigned)((c ^ (r & 7))*8);
    }
    const bf* Ap = A + (size_t)m0*K;
    const bf* Bp = B + (size_t)n0*K;

    auto stA = [&](int bb, int h, int kt) {
        bf* d = &AsL[bb][h][wid*1024];
        const bf* s = Ap + (size_t)h*128*K + (size_t)kt*64;
        gl_lds16(s + aOff[0], d);
        gl_lds16(s + aOff[1], d + 512);
    };
    auto stB = [&](int bb, int h, int kt) {
        bf* d = &BsL[bb][h][wid*1024];
        const bf* s = Bp + (size_t)h*128*K + (size_t)kt*64;
        gl_lds16(s + aOff[0], d);
        gl_lds16(s + aOff[1], d + 512);
    };

    f32x4 acc[8][4] = {};
    bf16x8 aR[4][2], bR0[2][2], bR1[2][2];

    // prologue: exact steady-state issue order, then wait all of kt=0
    stB(0,0,0); stB(0,1,0); stA(0,0,0); stA(0,1,0); stB(1,0,1); stB(1,1,1);
    asm volatile("s_waitcnt vmcnt(4)" ::: "memory");
    __builtin_amdgcn_s_barrier();

    const int brow0 = (wc & 1)*64;   // B row-in-half base for this wave
    for (int kt = 0; kt < NT; ++kt) {
        const int bb = kt & 1;
        const bf* Ab = &AsL[bb][wr][0];
        const bf* Bb = &BsL[bb][wc >> 1][0];

        // ---- phase 1: quad (m0,n0). ds: A-sub0 (8) + B-sub0 (4). stage Ah0(kt+1).
        #pragma unroll
        for (int mi = 0; mi < 4; ++mi)
            #pragma unroll
            for (int kk = 0; kk < 2; ++kk) {
                int r = mi*16 + l15;
                int kg = kk*4 + l4;
                aR[mi][kk] = *reinterpret_cast<const bf16x8*>(&Ab[r*64 + ((kg ^ (r & 7))*8)]);
            }
        #pragma unroll
        for (int ni = 0; ni < 2; ++ni)
            #pragma unroll
            for (int kk = 0; kk < 2; ++kk) {
                int r = brow0 + ni*16 + l15;
                int kg = kk*4 + l4;
                bR0[ni][kk] = *reinterpret_cast<const bf16x8*>(&Bb[r*64 + ((kg ^ (r & 7))*8)]);
            }
        if (kt + 1 < NT) stA(bb^1, 0, kt+1);
        __builtin_amdgcn_s_barrier();
        asm volatile("s_waitcnt lgkmcnt(0)" ::: "memory");
        __builtin_amdgcn_sched_barrier(0);
        __builtin_amdgcn_s_setprio(1);
        #pragma unroll
        for (int mi = 0; mi < 4; ++mi)
            #pragma unroll
            for (int ni = 0; ni < 2; ++ni)
                #pragma unroll
                for (int kk = 0; kk < 2; ++kk)
                    acc[mi][ni] = __builtin_amdgcn_mfma_f32_16x16x32_bf16(aR[mi][kk], bR0[ni][kk], acc[mi][ni], 0, 0, 0);
        __builtin_amdgcn_s_setprio(0);
        __builtin_amdgcn_s_barrier();

        // ---- phase 2: quad (m0,n1). ds: B-sub1 (4). stage Ah1(kt+1).
        #pragma unroll
        for (int ni = 0; ni < 2; ++ni)
            #pragma unroll
            for (int kk = 0; kk < 2; ++kk) {
                int r = brow0 + 32 + ni*16 + l15;
                int kg = kk*4 + l4;
                bR1[ni][kk] = *reinterpret_cast<const bf16x8*>(&Bb[r*64 + ((kg ^ (r & 7))*8)]);
            }
        if (kt + 1 < NT) stA(bb^1, 1, kt+1);
        __builtin_amdgcn_s_barrier();
        asm volatile("s_waitcnt lgkmcnt(0)" ::: "memory");
        __builtin_amdgcn_sched_barrier(0);
        __builtin_amdgcn_s_setprio(1);
        #pragma unroll
        for (int mi = 0; mi < 4; ++mi)
            #pragma unroll
            for (int ni = 0; ni < 2; ++ni)
                #pragma unroll
                for (int kk = 0; kk < 2; ++kk)
                    acc[mi][2+ni] = __builtin_amdgcn_mfma_f32_16x16x32_bf16(aR[mi][kk], bR1[ni][kk], acc[mi][2+ni], 0, 0, 0);
        __builtin_amdgcn_s_setprio(0);
        __builtin_amdgcn_s_barrier();

        // ---- phase 3: quad (m1,n1). ds: A-sub1 (8, overwrite aR). stage Bh0(kt+2).
        #pragma unroll
        for (int mi = 0; mi < 4; ++mi)
            #pragma unroll
            for (int kk = 0; kk < 2; ++kk) {
                int r = 64 + mi*16 + l15;
                int kg = kk*4 + l4;
                aR[mi][kk] = *reinterpret_cast<const bf16x8*>(&Ab[r*64 + ((kg ^ (r & 7))*8)]);
            }
        if (kt + 2 < NT) stB(bb, 0, kt+2);
        __builtin_amdgcn_s_barrier();
        asm volatile("s_waitcnt lgkmcnt(0)" ::: "memory");
        __builtin_amdgcn_sched_barrier(0);
        __builtin_amdgcn_s_setprio(1);
        #pragma unroll
        for (int mi = 0; mi < 4; ++mi)
            #pragma unroll
            for (int ni = 0; ni < 2; ++ni)
                #pragma unroll
                for (int kk = 0; kk < 2; ++kk)
                    acc[4+mi][2+ni] = __builtin_amdgcn_mfma_f32_16x16x32_bf16(aR[mi][kk], bR1[ni][kk], acc[4+mi][2+ni], 0, 0, 0);
        __builtin_amdgcn_s_setprio(0);
        __builtin_amdgcn_s_barrier();

        // ---- phase 4: quad (m1,n0). no ds. stage Bh1(kt+2). counted vmcnt.
        if (kt + 2 < NT) stB(bb, 1, kt+2);
        if (kt >= NT-2) asm volatile("s_waitcnt vmcnt(0)" ::: "memory");
        else            asm volatile("s_waitcnt vmcnt(4)" ::: "memory");
        __builtin_amdgcn_s_barrier();
        __builtin_amdgcn_s_setprio(1);
        #pragma unroll
        for (int mi = 0; mi < 4; ++mi)
            #pragma unroll
            for (int ni = 0; ni < 2; ++ni)
                #pragma unroll
                for (int kk = 0; kk < 2; ++kk)
                    acc[4+mi][ni] = __builtin_amdgcn_mfma_f32_16x16x32_bf16(aR[mi][kk], bR0[ni][kk], acc[4+mi][ni], 0, 0, 0);
        __builtin_amdgcn_s_setprio(0);
        __builtin_amdgcn_s_barrier();
    }

    // epilogue
    const int cr0 = m0 + wr*128, cc0 = n0 + wc*64;
    #pragma unroll
    for (int NI = 0; NI < 4; ++NI) {
        int colg = cc0 + NI*16 + l15;
        float bv = bias[colg];
        #pragma unroll
        for (int MI = 0; MI < 8; ++MI)
            #pragma unroll
            for (int rr = 0; rr < 4; ++rr) {
                int rowg = cr0 + MI*16 + l4*4 + rr;
                float v = acc[MI][NI][rr] + bv;
                if (OUTBF) ((bf*)Cp)[(size_t)rowg*N + colg] = (bf)v;
                else       ((float*)Cp)[(size_t)rowg*N + colg] = v;
            }
    }
}

// ---------------- V repack: qkv[b,s,2E + h*D + d] -> vt[bh, d, s] ----------------
__global__ void repack_vt(const bf* __restrict__ qkv, bf* __restrict__ vt) {
    __shared__ bf tile[64][72];
    const int bh = blockIdx.z, b = bh >> 3, h = bh & 7;
    const int s0 = blockIdx.x*64, d0 = blockIdx.y*64;
    const int t = threadIdx.x;
    #pragma unroll
    for (int p = 0; p < 2; ++p) {
        int sr = (t >> 3) + p*32, ck = t & 7;
        s16x8 v = *reinterpret_cast<const s16x8*>(
            qkv + ((size_t)(b*SEQ + s0 + sr))*FTOT + 2*EMBED + h*HDIM + d0 + ck*8);
        *reinterpret_cast<s16x8*>(&tile[sr][ck*8]) = v;
    }
    __syncthreads();
    #pragma unroll
    for (int p = 0; p < 2; ++p) {
        int dr = (t >> 3) + p*32, ck = t & 7;
        bf16x8 r;
        #pragma unroll
        for (int j = 0; j < 8; ++j) r[j] = tile[ck*8 + j][dr];
        *reinterpret_cast<bf16x8*>(vt + ((size_t)bh*HDIM + d0 + dr)*SEQ + s0 + ck*8) = r;
    }
}

// ---------------- flash attention v3 (unchanged) ----------------
__global__ __launch_bounds__(512, 2)
void attn_fwd(const bf* __restrict__ qkv, const bf* __restrict__ vt, bf* __restrict__ aout) {
    __shared__ bf Kls[2][32*320];
    __shared__ bf Vls[2][320*32];
    __shared__ bf Ps[8][16][40];
    const int bh = blockIdx.y, b = bh >> 3, h = bh & 7;
    const int tid = threadIdx.x, lane = tid & 63, wid = tid >> 6;
    const int qw = blockIdx.x*128 + wid*16;
    const int l15 = lane & 15, l4 = lane >> 4;
    const float scale = 0.05590169944f;

    const bf* gsrc[5];
    int ldsoff[5];
    size_t step;
    if (wid < 4) {
        step = (size_t)32*FTOT;
        #pragma unroll
        for (int i = 0; i < 5; ++i) {
            int g = wid*5 + i;
            int q = g*64 + lane;
            int r = q/40, cl = q - r*40;
            int cg = cl ^ (r & 7);
            gsrc[i] = qkv + (size_t)(b*SEQ + r)*FTOT + EMBED + h*HDIM + cg*8;
            ldsoff[i] = g*512;
        }
    } else {
        step = 32;
        #pragma unroll
        for (int i = 0; i < 5; ++i) {
            int g = wid*5 + i - 20;
            int q = g*64 + lane;
            int row = q >> 2, cl = q & 3;
            int cg = cl ^ ((row >> 1) & 3);
            gsrc[i] = vt + (size_t)bh*HDIM*SEQ + (size_t)row*SEQ + cg*8;
            ldsoff[i] = g*512;
        }
    }

    bf16x8 qf[10];
    const bf* qbase = qkv + ((size_t)(b*SEQ + qw + l15))*FTOT + h*HDIM + l4*8;
    #pragma unroll
    for (int d = 0; d < 10; ++d) qf[d] = *reinterpret_cast<const bf16x8*>(qbase + d*32);

    f32x4 o[20] = {};
    float mrow[4], lsum[4];
    #pragma unroll
    for (int r = 0; r < 4; ++r) { mrow[r] = -1e30f; lsum[r] = 0.f; }

    const int r7  = l15 & 7;
    const int vsw = (l4 ^ ((l15 >> 1) & 3))*8;

    {
        bf* lb = (wid < 4) ? &Kls[0][0] : &Vls[0][0];
        #pragma unroll
        for (int i = 0; i < 5; ++i) { gl_lds16(gsrc[i], lb + ldsoff[i]); gsrc[i] += step; }
    }
    __syncthreads();

    for (int kt = 0; kt < SEQ/32; ++kt) {
        const int bb = kt & 1;
        if (kt + 1 < SEQ/32) {
            bf* lb = (wid < 4) ? &Kls[bb^1][0] : &Vls[bb^1][0];
            #pragma unroll
            for (int i = 0; i < 5; ++i) { gl_lds16(gsrc[i], lb + ldsoff[i]); gsrc[i] += step; }
        }
        const bf* Kb = &Kls[bb][0];
        const bf* Vb = &Vls[bb][0];

        f32x4 sc[2] = {};
        #pragma unroll
        for (int kb = 0; kb < 2; ++kb) {
            const int Rbase = (kb*16 + l15)*320;
            #pragma unroll
            for (int d = 0; d < 10; ++d) {
                int c = (d*4 + l4) ^ r7;
                bf16x8 kf = *reinterpret_cast<const bf16x8*>(&Kb[Rbase + c*8]);
                sc[kb] = __builtin_amdgcn_mfma_f32_16x16x32_bf16(qf[d], kf, sc[kb], 0, 0, 0);
            }
        }

        float tmax[4];
        bool need = false;
        #pragma unroll
        for (int r = 0; r < 4; ++r) {
            float v = fmaxf(sc[0][r], sc[1][r])*scale;
            v = fmaxf(v, __shfl_xor(v, 1));
            v = fmaxf(v, __shfl_xor(v, 2));
            v = fmaxf(v, __shfl_xor(v, 4));
            v = fmaxf(v, __shfl_xor(v, 8));
            tmax[r] = v;
            need = need || (v > mrow[r] + 8.f);
        }
        if (__any(need)) {
            float alpha[4];
            #pragma unroll
            for (int r = 0; r < 4; ++r) {
                float nm = fmaxf(mrow[r], tmax[r]);
                alpha[r] = __expf(mrow[r] - nm);
                mrow[r] = nm;
                lsum[r] *= alpha[r];
            }
            #pragma unroll
            for (int c = 0; c < 20; ++c)
                #pragma unroll
                for (int r = 0; r < 4; ++r) o[c][r] *= alpha[r];
        }

        float ps[2][4];
        #pragma unroll
        for (int r = 0; r < 4; ++r) {
            float p0 = __expf(sc[0][r]*scale - mrow[r]);
            float p1 = __expf(sc[1][r]*scale - mrow[r]);
            ps[0][r] = p0; ps[1][r] = p1;
            lsum[r] += p0 + p1;
        }

        #pragma unroll
        for (int kb = 0; kb < 2; ++kb)
            #pragma unroll
            for (int r = 0; r < 4; ++r)
                Ps[wid][l4*4 + r][kb*16 + l15] = (bf)ps[kb][r];

        bf16x8 pf = *reinterpret_cast<const bf16x8*>(&Ps[wid][l15][l4*8]);
        #pragma unroll
        for (int c = 0; c < 20; ++c) {
            bf16x8 vf = *reinterpret_cast<const bf16x8*>(&Vb[(c*16 + l15)*32 + vsw]);
            o[c] = __builtin_amdgcn_mfma_f32_16x16x32_bf16(pf, vf, o[c], 0, 0, 0);
        }
        __syncthreads();
    }

    float inv[4];
    #pragma unroll
    for (int r = 0; r < 4; ++r) {
        float s = lsum[r];
        s += __shfl_xor(s, 1);
        s += __shfl_xor(s, 2);
        s += __shfl_xor(s, 4);
        s += __shfl_xor(s, 8);
        inv[r] = 1.f/s;
    }
    #pragma unroll
    for (int c = 0; c < 20; ++c)
        #pragma unroll
        for (int r = 0; r < 4; ++r) {
            size_t idx = ((size_t)(b*SEQ + qw + l4*4 + r))*EMBED + h*HDIM + c*16 + l15;
            aout[idx] = (bf)(o[c][r]*inv[r]);
        }
}

// ---------------- launch ----------------
extern "C" void kernel_launch(void* const* d_in, const int* in_sizes, int n_in,
                              void* d_out, int out_size, void* d_ws, size_t ws_size,
                              hipStream_t stream) {
    const float* x    = (const float*)d_in[0];
    const float* Wqkv = (const float*)d_in[1];
    const float* bqkv = (const float*)d_in[2];
    const float* Wout = (const float*)d_in[3];
    const float* bout = (const float*)d_in[4];
    float* out = (float*)d_out;

    char* ws = (char*)d_ws;
    bf* xb    = (bf*)(ws);                         // 20,971,520 B
    bf* wqkvb = (bf*)(ws + 20971520);              // 39,321,600 B
    bf* woutb = (bf*)(ws + 60293120);              // 13,107,200 B
    bf* qkvb  = (bf*)(ws + 73400320);              // 62,914,560 B
    bf* vtb   = (bf*)(ws + 136314880);             // 20,971,520 B -> total 157,286,400
    bf* attnb = xb;                                // alias: x consumed by gemm1

    cvt_bf16<<<5120, 256, 0, stream>>>(x,    xb,    MTOT*EMBED);
    cvt_bf16<<<9600, 256, 0, stream>>>(Wqkv, wqkvb, FTOT*EMBED);
    cvt_bf16<<<3200, 256, 0, stream>>>(Wout, woutb, EMBED*EMBED);

    gemm256<true ><<<dim3(FTOT/256,  MTOT/256), 512, 0, stream>>>(xb, wqkvb, bqkv, qkvb, MTOT, FTOT, EMBED);
    repack_vt<<<dim3(SEQ/64, HDIM/64, BATCH*HEADS), 256, 0, stream>>>(qkvb, vtb);
    attn_fwd<<<dim3(SEQ/128, BATCH*HEADS), 512, 0, stream>>>(qkvb, vtb, attnb);
    gemm256<false><<<dim3(EMBED/256, MTOT/256), 512, 0, stream>>>(attnb, woutb, bout, out, MTOT, EMBED, EMBED);
}

// Round 9
// 417.151 us; speedup vs baseline: 2.6338x; 1.0004x over previous
//
#include <hip/hip_runtime.h>

#define EMBED 2560
#define HEADS 8
#define HDIM  320
#define BATCH 2
#define SEQ   2048
#define MTOT  (BATCH*SEQ)   // 4096
#define FTOT  (3*EMBED)     // 7680

using bf = __bf16;
typedef __bf16 bf16x8 __attribute__((ext_vector_type(8)));
typedef float  f32x4  __attribute__((ext_vector_type(4)));
typedef short  s16x8  __attribute__((ext_vector_type(8)));
typedef float  f32x4v __attribute__((ext_vector_type(4)));

__device__ __forceinline__ void gl_lds16(const bf* g, bf* l) {
    __builtin_amdgcn_global_load_lds(
        (const __attribute__((address_space(1))) void*)g,
        (__attribute__((address_space(3))) void*)l,
        16, 0, 0);
}

// ---------------- fp32 -> bf16 convert ----------------
__global__ void cvt_bf16(const float* __restrict__ in, bf* __restrict__ out, int n) {
    int i = (blockIdx.x*blockDim.x + threadIdx.x)*8;
    if (i >= n) return;
    f32x4v a = *reinterpret_cast<const f32x4v*>(in + i);
    f32x4v b = *reinterpret_cast<const f32x4v*>(in + i + 4);
    bf16x8 r;
    r[0]=(bf)a[0]; r[1]=(bf)a[1]; r[2]=(bf)a[2]; r[3]=(bf)a[3];
    r[4]=(bf)b[0]; r[5]=(bf)b[1]; r[6]=(bf)b[2]; r[7]=(bf)b[3];
    *reinterpret_cast<bf16x8*>(out + i) = r;
}

// ============ 8-phase 256x256 NT GEMM: C[M,N] = A[M,K] @ B[N,K]^T + bias ============
// BK=64, 8 waves (2M x 4N), wave tile 128x64. LDS 128 KiB. Counted vmcnt(4) once per
// K-tile. 3-bit XOR granule swizzle (0 conflicts, verified r8). This round: NO manual
// lgkmcnt(0)/sched_barrier pins -- let the compiler emit fine-grained counted lgkmcnt
// so per-wave MFMA overlaps in-flight ds_reads (the r8 serialization fix).
template<bool OUTBF>
__global__ __launch_bounds__(512, 2)
void gemm256(const bf* __restrict__ A, const bf* __restrict__ B,
             const float* __restrict__ bias, void* __restrict__ Cp,
             int M, int N, int K) {
    __shared__ __align__(16) bf AsL[2][2][8192];
    __shared__ __align__(16) bf BsL[2][2][8192];
    const int tid = threadIdx.x, lane = tid & 63, wid = tid >> 6;
    const int wr = wid >> 2, wc = wid & 3;
    const int l15 = lane & 15, l4 = lane >> 4;

    // bijective XCD swizzle (grids here are multiples of 8)
    const int nwg = gridDim.x*gridDim.y;
    int bid = blockIdx.y*gridDim.x + blockIdx.x;
    if ((nwg & 7) == 0) bid = (bid & 7)*(nwg >> 3) + (bid >> 3);
    const int m0 = (bid / gridDim.x)*256, n0 = (bid % gridDim.x)*256;
    const int NT = K >> 6;

    // staging: LDS linear dest; lane l of instr (wid*2+j) holds LDS granule
    // q=(wid*2+j)*64+l -> row=q>>3, slot c=q&7, global k-granule = c^(row&7).
    unsigned aOff[2];
    #pragma unroll
    for (int j = 0; j < 2; ++j) {
        int q = (wid*2 + j)*64 + lane;
        int r = q >> 3, c = q & 7;
        aOff[j] = (unsigned)r*K + (unsigned)((c ^ (r & 7))*8);
    }
    const bf* Ap = A + (size_t)m0*K;
    const bf* Bp = B + (size_t)n0*K;

    auto stA = [&](int bb, int h, int kt) {
        bf* d = &AsL[bb][h][wid*1024];
        const bf* s = Ap + (size_t)h*128*K + (size_t)kt*64;
        gl_lds16(s + aOff[0], d);
        gl_lds16(s + aOff[1], d + 512);
    };
    auto stB = [&](int bb, int h, int kt) {
        bf* d = &BsL[bb][h][wid*1024];
        const bf* s = Bp + (size_t)h*128*K + (size_t)kt*64;
        gl_lds16(s + aOff[0], d);
        gl_lds16(s + aOff[1], d + 512);
    };

    f32x4 acc[8][4] = {};
    bf16x8 aR[4][2], bR0[2][2], bR1[2][2];

    // prologue: exact steady-state issue order, then wait all of kt=0
    stB(0,0,0); stB(0,1,0); stA(0,0,0); stA(0,1,0); stB(1,0,1); stB(1,1,1);
    asm volatile("s_waitcnt vmcnt(4)" ::: "memory");
    __builtin_amdgcn_s_barrier();

    const int brow0 = (wc & 1)*64;   // B row-in-half base for this wave
    for (int kt = 0; kt < NT; ++kt) {
        const int bb = kt & 1;
        const bf* Ab = &AsL[bb][wr][0];
        const bf* Bb = &BsL[bb][wc >> 1][0];

        // ---- phase 1: quad (m0,n0). ds: A-sub0 (8) + B-sub0 (4). stage Ah0(kt+1).
        #pragma unroll
        for (int mi = 0; mi < 4; ++mi)
            #pragma unroll
            for (int kk = 0; kk < 2; ++kk) {
                int r = mi*16 + l15;
                int kg = kk*4 + l4;
                aR[mi][kk] = *reinterpret_cast<const bf16x8*>(&Ab[r*64 + ((kg ^ (r & 7))*8)]);
            }
        #pragma unroll
        for (int ni = 0; ni < 2; ++ni)
            #pragma unroll
            for (int kk = 0; kk < 2; ++kk) {
                int r = brow0 + ni*16 + l15;
                int kg = kk*4 + l4;
                bR0[ni][kk] = *reinterpret_cast<const bf16x8*>(&Bb[r*64 + ((kg ^ (r & 7))*8)]);
            }
        if (kt + 1 < NT) stA(bb^1, 0, kt+1);
        __builtin_amdgcn_s_barrier();
        __builtin_amdgcn_s_setprio(1);
        #pragma unroll
        for (int mi = 0; mi < 4; ++mi)
            #pragma unroll
            for (int ni = 0; ni < 2; ++ni)
                #pragma unroll
                for (int kk = 0; kk < 2; ++kk)
                    acc[mi][ni] = __builtin_amdgcn_mfma_f32_16x16x32_bf16(aR[mi][kk], bR0[ni][kk], acc[mi][ni], 0, 0, 0);
        __builtin_amdgcn_s_setprio(0);
        __builtin_amdgcn_s_barrier();

        // ---- phase 2: quad (m0,n1). ds: B-sub1 (4). stage Ah1(kt+1).
        #pragma unroll
        for (int ni = 0; ni < 2; ++ni)
            #pragma unroll
            for (int kk = 0; kk < 2; ++kk) {
                int r = brow0 + 32 + ni*16 + l15;
                int kg = kk*4 + l4;
                bR1[ni][kk] = *reinterpret_cast<const bf16x8*>(&Bb[r*64 + ((kg ^ (r & 7))*8)]);
            }
        if (kt + 1 < NT) stA(bb^1, 1, kt+1);
        __builtin_amdgcn_s_barrier();
        __builtin_amdgcn_s_setprio(1);
        #pragma unroll
        for (int mi = 0; mi < 4; ++mi)
            #pragma unroll
            for (int ni = 0; ni < 2; ++ni)
                #pragma unroll
                for (int kk = 0; kk < 2; ++kk)
                    acc[mi][2+ni] = __builtin_amdgcn_mfma_f32_16x16x32_bf16(aR[mi][kk], bR1[ni][kk], acc[mi][2+ni], 0, 0, 0);
        __builtin_amdgcn_s_setprio(0);
        __builtin_amdgcn_s_barrier();

        // ---- phase 3: quad (m1,n1). ds: A-sub1 (8, overwrite aR). stage Bh0(kt+2).
        #pragma unroll
        for (int mi = 0; mi < 4; ++mi)
            #pragma unroll
            for (int kk = 0; kk < 2; ++kk) {
                int r = 64 + mi*16 + l15;
                int kg = kk*4 + l4;
                aR[mi][kk] = *reinterpret_cast<const bf16x8*>(&Ab[r*64 + ((kg ^ (r & 7))*8)]);
            }
        if (kt + 2 < NT) stB(bb, 0, kt+2);
        __builtin_amdgcn_s_barrier();
        __builtin_amdgcn_s_setprio(1);
        #pragma unroll
        for (int mi = 0; mi < 4; ++mi)
            #pragma unroll
            for (int ni = 0; ni < 2; ++ni)
                #pragma unroll
                for (int kk = 0; kk < 2; ++kk)
                    acc[4+mi][2+ni] = __builtin_amdgcn_mfma_f32_16x16x32_bf16(aR[mi][kk], bR1[ni][kk], acc[4+mi][2+ni], 0, 0, 0);
        __builtin_amdgcn_s_setprio(0);
        __builtin_amdgcn_s_barrier();

        // ---- phase 4: quad (m1,n0). no ds. stage Bh1(kt+2). counted vmcnt.
        if (kt + 2 < NT) stB(bb, 1, kt+2);
        if (kt >= NT-2) asm volatile("s_waitcnt vmcnt(0)" ::: "memory");
        else            asm volatile("s_waitcnt vmcnt(4)" ::: "memory");
        __builtin_amdgcn_s_barrier();
        __builtin_amdgcn_s_setprio(1);
        #pragma unroll
        for (int mi = 0; mi < 4; ++mi)
            #pragma unroll
            for (int ni = 0; ni < 2; ++ni)
                #pragma unroll
                for (int kk = 0; kk < 2; ++kk)
                    acc[4+mi][ni] = __builtin_amdgcn_mfma_f32_16x16x32_bf16(aR[mi][kk], bR0[ni][kk], acc[4+mi][ni], 0, 0, 0);
        __builtin_amdgcn_s_setprio(0);
        __builtin_amdgcn_s_barrier();
    }

    // epilogue
    const int cr0 = m0 + wr*128, cc0 = n0 + wc*64;
    #pragma unroll
    for (int NI = 0; NI < 4; ++NI) {
        int colg = cc0 + NI*16 + l15;
        float bv = bias[colg];
        #pragma unroll
        for (int MI = 0; MI < 8; ++MI)
            #pragma unroll
            for (int rr = 0; rr < 4; ++rr) {
                int rowg = cr0 + MI*16 + l4*4 + rr;
                float v = acc[MI][NI][rr] + bv;
                if (OUTBF) ((bf*)Cp)[(size_t)rowg*N + colg] = (bf)v;
                else       ((float*)Cp)[(size_t)rowg*N + colg] = v;
            }
    }
}

// ---------------- V repack: qkv[b,s,2E + h*D + d] -> vt[bh, d, s] ----------------
__global__ void repack_vt(const bf* __restrict__ qkv, bf* __restrict__ vt) {
    __shared__ bf tile[64][72];
    const int bh = blockIdx.z, b = bh >> 3, h = bh & 7;
    const int s0 = blockIdx.x*64, d0 = blockIdx.y*64;
    const int t = threadIdx.x;
    #pragma unroll
    for (int p = 0; p < 2; ++p) {
        int sr = (t >> 3) + p*32, ck = t & 7;
        s16x8 v = *reinterpret_cast<const s16x8*>(
            qkv + ((size_t)(b*SEQ + s0 + sr))*FTOT + 2*EMBED + h*HDIM + d0 + ck*8);
        *reinterpret_cast<s16x8*>(&tile[sr][ck*8]) = v;
    }
    __syncthreads();
    #pragma unroll
    for (int p = 0; p < 2; ++p) {
        int dr = (t >> 3) + p*32, ck = t & 7;
        bf16x8 r;
        #pragma unroll
        for (int j = 0; j < 8; ++j) r[j] = tile[ck*8 + j][dr];
        *reinterpret_cast<bf16x8*>(vt + ((size_t)bh*HDIM + d0 + dr)*SEQ + s0 + ck*8) = r;
    }
}

// ---------------- flash attention v3 (unchanged) ----------------
__global__ __launch_bounds__(512, 2)
void attn_fwd(const bf* __restrict__ qkv, const bf* __restrict__ vt, bf* __restrict__ aout) {
    __shared__ bf Kls[2][32*320];
    __shared__ bf Vls[2][320*32];
    __shared__ bf Ps[8][16][40];
    const int bh = blockIdx.y, b = bh >> 3, h = bh & 7;
    const int tid = threadIdx.x, lane = tid & 63, wid = tid >> 6;
    const int qw = blockIdx.x*128 + wid*16;
    const int l15 = lane & 15, l4 = lane >> 4;
    const float scale = 0.05590169944f;

    const bf* gsrc[5];
    int ldsoff[5];
    size_t step;
    if (wid < 4) {
        step = (size_t)32*FTOT;
        #pragma unroll
        for (int i = 0; i < 5; ++i) {
            int g = wid*5 + i;
            int q = g*64 + lane;
            int r = q/40, cl = q - r*40;
            int cg = cl ^ (r & 7);
            gsrc[i] = qkv + (size_t)(b*SEQ + r)*FTOT + EMBED + h*HDIM + cg*8;
            ldsoff[i] = g*512;
        }
    } else {
        step = 32;
        #pragma unroll
        for (int i = 0; i < 5; ++i) {
            int g = wid*5 + i - 20;
            int q = g*64 + lane;
            int row = q >> 2, cl = q & 3;
            int cg = cl ^ ((row >> 1) & 3);
            gsrc[i] = vt + (size_t)bh*HDIM*SEQ + (size_t)row*SEQ + cg*8;
            ldsoff[i] = g*512;
        }
    }

    bf16x8 qf[10];
    const bf* qbase = qkv + ((size_t)(b*SEQ + qw + l15))*FTOT + h*HDIM + l4*8;
    #pragma unroll
    for (int d = 0; d < 10; ++d) qf[d] = *reinterpret_cast<const bf16x8*>(qbase + d*32);

    f32x4 o[20] = {};
    float mrow[4], lsum[4];
    #pragma unroll
    for (int r = 0; r < 4; ++r) { mrow[r] = -1e30f; lsum[r] = 0.f; }

    const int r7  = l15 & 7;
    const int vsw = (l4 ^ ((l15 >> 1) & 3))*8;

    {
        bf* lb = (wid < 4) ? &Kls[0][0] : &Vls[0][0];
        #pragma unroll
        for (int i = 0; i < 5; ++i) { gl_lds16(gsrc[i], lb + ldsoff[i]); gsrc[i] += step; }
    }
    __syncthreads();

    for (int kt = 0; kt < SEQ/32; ++kt) {
        const int bb = kt & 1;
        if (kt + 1 < SEQ/32) {
            bf* lb = (wid < 4) ? &Kls[bb^1][0] : &Vls[bb^1][0];
            #pragma unroll
            for (int i = 0; i < 5; ++i) { gl_lds16(gsrc[i], lb + ldsoff[i]); gsrc[i] += step; }
        }
        const bf* Kb = &Kls[bb][0];
        const bf* Vb = &Vls[bb][0];

        f32x4 sc[2] = {};
        #pragma unroll
        for (int kb = 0; kb < 2; ++kb) {
            const int Rbase = (kb*16 + l15)*320;
            #pragma unroll
            for (int d = 0; d < 10; ++d) {
                int c = (d*4 + l4) ^ r7;
                bf16x8 kf = *reinterpret_cast<const bf16x8*>(&Kb[Rbase + c*8]);
                sc[kb] = __builtin_amdgcn_mfma_f32_16x16x32_bf16(qf[d], kf, sc[kb], 0, 0, 0);
            }
        }

        float tmax[4];
        bool need = false;
        #pragma unroll
        for (int r = 0; r < 4; ++r) {
            float v = fmaxf(sc[0][r], sc[1][r])*scale;
            v = fmaxf(v, __shfl_xor(v, 1));
            v = fmaxf(v, __shfl_xor(v, 2));
            v = fmaxf(v, __shfl_xor(v, 4));
            v = fmaxf(v, __shfl_xor(v, 8));
            tmax[r] = v;
            need = need || (v > mrow[r] + 8.f);
        }
        if (__any(need)) {
            float alpha[4];
            #pragma unroll
            for (int r = 0; r < 4; ++r) {
                float nm = fmaxf(mrow[r], tmax[r]);
                alpha[r] = __expf(mrow[r] - nm);
                mrow[r] = nm;
                lsum[r] *= alpha[r];
            }
            #pragma unroll
            for (int c = 0; c < 20; ++c)
                #pragma unroll
                for (int r = 0; r < 4; ++r) o[c][r] *= alpha[r];
        }

        float ps[2][4];
        #pragma unroll
        for (int r = 0; r < 4; ++r) {
            float p0 = __expf(sc[0][r]*scale - mrow[r]);
            float p1 = __expf(sc[1][r]*scale - mrow[r]);
            ps[0][r] = p0; ps[1][r] = p1;
            lsum[r] += p0 + p1;
        }

        #pragma unroll
        for (int kb = 0; kb < 2; ++kb)
            #pragma unroll
            for (int r = 0; r < 4; ++r)
                Ps[wid][l4*4 + r][kb*16 + l15] = (bf)ps[kb][r];

        bf16x8 pf = *reinterpret_cast<const bf16x8*>(&Ps[wid][l15][l4*8]);
        #pragma unroll
        for (int c = 0; c < 20; ++c) {
            bf16x8 vf = *reinterpret_cast<const bf16x8*>(&Vb[(c*16 + l15)*32 + vsw]);
            o[c] = __builtin_amdgcn_mfma_f32_16x16x32_bf16(pf, vf, o[c], 0, 0, 0);
        }
        __syncthreads();
    }

    float inv[4];
    #pragma unroll
    for (int r = 0; r < 4; ++r) {
        float s = lsum[r];
        s += __shfl_xor(s, 1);
        s += __shfl_xor(s, 2);
        s += __shfl_xor(s, 4);
        s += __shfl_xor(s, 8);
        inv[r] = 1.f/s;
    }
    #pragma unroll
    for (int c = 0; c < 20; ++c)
        #pragma unroll
        for (int r = 0; r < 4; ++r) {
            size_t idx = ((size_t)(b*SEQ + qw + l4*4 + r))*EMBED + h*HDIM + c*16 + l15;
            aout[idx] = (bf)(o[c][r]*inv[r]);
        }
}

// ---------------- launch ----------------
extern "C" void kernel_launch(void* const* d_in, const int* in_sizes, int n_in,
                              void* d_out, int out_size, void* d_ws, size_t ws_size,
                              hipStream_t stream) {
    const float* x    = (const float*)d_in[0];
    const float* Wqkv = (const float*)d_in[1];
    const float* bqkv = (const float*)d_in[2];
    const float* Wout = (const float*)d_in[3];
    const float* bout = (const float*)d_in[4];
    float* out = (float*)d_out;

    char* ws = (char*)d_ws;
    bf* xb    = (bf*)(ws);                         // 20,971,520 B
    bf* wqkvb = (bf*)(ws + 20971520);              // 39,321,600 B
    bf* woutb = (bf*)(ws + 60293120);              // 13,107,200 B
    bf* qkvb  = (bf*)(ws + 73400320);              // 62,914,560 B
    bf* vtb   = (bf*)(ws + 136314880);             // 20,971,520 B -> total 157,286,400
    bf* attnb = xb;                                // alias: x consumed by gemm1

    cvt_bf16<<<5120, 256, 0, stream>>>(x,    xb,    MTOT*EMBED);
    cvt_bf16<<<9600, 256, 0, stream>>>(Wqkv, wqkvb, FTOT*EMBED);
    cvt_bf16<<<3200, 256, 0, stream>>>(Wout, woutb, EMBED*EMBED);

    gemm256<true ><<<dim3(FTOT/256,  MTOT/256), 512, 0, stream>>>(xb, wqkvb, bqkv, qkvb, MTOT, FTOT, EMBED);
    repack_vt<<<dim3(SEQ/64, HDIM/64, BATCH*HEADS), 256, 0, stream>>>(qkvb, vtb);
    attn_fwd<<<dim3(SEQ/128, BATCH*HEADS), 512, 0, stream>>>(qkvb, vtb, attnb);
    gemm256<false><<<dim3(EMBED/256, MTOT/256), 512, 0, stream>>>(attnb, woutb, bout, out, MTOT, EMBED, EMBED);
}